// Round 9
// baseline (196.041 us; speedup 1.0000x reference)
//
#include <hip/hip_runtime.h>
#include <hip/hip_fp16.h>

// out[n,a,b] = sigmoid(w2 . leaky(w1 . leaky(u'[n,a,:] - v[n,b,:]) + b1) + b2)
// u' = za.w0^T + b0, v = zb.w0^T (precomputed f16).
// Algebra: leaky(x) = 0.505x + 0.495|x| (exact for slope 0.01), so
//   w1 . leaky(u-v) + b1 = [0.505(P[a,g]-Q[b,g]) + b1[g]] + (0.495 w1) . |u-v|
// with P = u'.w1^T, Q = v.w1^T precomputed from the SAME f16-rounded u,v.
// Main GEMM: A = 0.495*w1 stationary in regs, B = |u-v| built with pk_sub +
// and-mask only (8 clean VALU/kt). Affine part folded into MFMA C-init.
// Block = 8 waves (512 thr); wave ws owns g-tile ws (w1f[16] = 64 regs);
// block owns (n,bblk): vf[16] = 64 regs. Grid 256 = n(8) x bblk(8) x aq(4).

typedef float f32x16 __attribute__((ext_vector_type(16)));
typedef _Float16 f16x8 __attribute__((ext_vector_type(8)));
typedef int i32x4 __attribute__((ext_vector_type(4)));

// ---------------------------------------------------------------------------
// Merged pack kernel.
// Blocks 0..2047: u' (f16 linear), v (f16 B-frag-linear), v (f16 linear).
// Blocks 2048..2303: 0.495*w1 into A-frag-linear f16.
// ---------------------------------------------------------------------------
__global__ __launch_bounds__(256) void pack_all(
    const float* __restrict__ za, const float* __restrict__ zb,
    const float* __restrict__ w0, const float* __restrict__ b0,
    const float* __restrict__ w1,
    _Float16* __restrict__ upack, _Float16* __restrict__ vpack,
    _Float16* __restrict__ vlin, _Float16* __restrict__ w1pk) {
  int bid = blockIdx.x;
  int tid = threadIdx.x;
  if (bid < 2048) {
    int nr = bid;                   // n*256 + r
    int n = nr >> 8, r = nr & 255;
    __shared__ float arow[64], brow[64];
    if (tid < 64) arow[tid] = za[nr * 64 + tid];
    else if (tid < 128) brow[tid - 64] = zb[nr * 64 + (tid - 64)];
    __syncthreads();
    int h = tid;
    const float* w0r = w0 + h * 64;
    float ua = 0.f, vb = 0.f;
#pragma unroll
    for (int c = 0; c < 64; c += 4) {
      float4 w = *reinterpret_cast<const float4*>(w0r + c);
      ua += w.x * arow[c] + w.y * arow[c + 1] + w.z * arow[c + 2] + w.w * arow[c + 3];
      vb += w.x * brow[c] + w.y * brow[c + 1] + w.z * brow[c + 2] + w.w * brow[c + 3];
    }
    upack[nr * 256 + h] = (_Float16)(ua + b0[h]);
    _Float16 vh = (_Float16)vb;
    vlin[nr * 256 + h] = vh;
    // v B-frag-linear: frag (n, bblk=r>>5, kiter=h>>4); lane = lh*32 + (r&31)
    int bblk = r >> 5, lcol = r & 31;
    int kiter = h >> 4, rem = h & 15, lh = rem >> 3, j = rem & 7;
    int lane = lh * 32 + lcol;
    vpack[(((n * 8 + bblk) * 16 + kiter) * 64 + lane) * 8 + j] = vh;
  } else {
    int id = (bid - 2048) * 256 + tid;   // 0..65535
    int g = id >> 8, k = id & 255;
    int gt = g >> 5, lcol = g & 31;
    int kiter = k >> 4, rem = k & 15, lh = rem >> 3, j = rem & 7;
    int lane = lh * 32 + lcol;
    w1pk[((kiter * 8 + gt) * 64 + lane) * 8 + j] = (_Float16)(0.495f * w1[id]);
  }
}

// ---------------------------------------------------------------------------
// P/Q precompute: Ra[nr,g] = 0.505*sum_k w1[g,k]*u'[nr,k] + b1[g]
//                 Sb[nr,g] = 0.505*sum_k w1[g,k]*v[nr,k]
// grid 1024 = which(2) x nr4(512); block 256 (thread = g); 4 rows per block.
// ---------------------------------------------------------------------------
__global__ __launch_bounds__(256) void pq_kernel(
    const _Float16* __restrict__ upack, const _Float16* __restrict__ vlin,
    const float* __restrict__ w1, const float* __restrict__ b1,
    float* __restrict__ Ra, float* __restrict__ Sb) {
  int bid = blockIdx.x;
  int which = bid >> 9;
  int nr0 = (bid & 511) * 4;
  __shared__ float rows[4][256];
  int tid = threadIdx.x;
  const _Float16* src = which ? vlin : upack;
#pragma unroll
  for (int i = 0; i < 4; ++i)
    rows[i][tid] = (float)src[(size_t)(nr0 + i) * 256 + tid];
  __syncthreads();
  int g = tid;
  const float* w1r = w1 + (size_t)g * 256;
  float acc0 = 0.f, acc1 = 0.f, acc2 = 0.f, acc3 = 0.f;
#pragma unroll 8
  for (int k = 0; k < 256; k += 4) {
    float4 w = *reinterpret_cast<const float4*>(w1r + k);
    acc0 += w.x * rows[0][k] + w.y * rows[0][k + 1] + w.z * rows[0][k + 2] + w.w * rows[0][k + 3];
    acc1 += w.x * rows[1][k] + w.y * rows[1][k + 1] + w.z * rows[1][k + 2] + w.w * rows[1][k + 3];
    acc2 += w.x * rows[2][k] + w.y * rows[2][k + 1] + w.z * rows[2][k + 2] + w.w * rows[2][k + 3];
    acc3 += w.x * rows[3][k] + w.y * rows[3][k + 1] + w.z * rows[3][k + 2] + w.w * rows[3][k + 3];
  }
  if (which == 0) {
    float bb = b1[g];
    Ra[(size_t)(nr0 + 0) * 256 + g] = 0.505f * acc0 + bb;
    Ra[(size_t)(nr0 + 1) * 256 + g] = 0.505f * acc1 + bb;
    Ra[(size_t)(nr0 + 2) * 256 + g] = 0.505f * acc2 + bb;
    Ra[(size_t)(nr0 + 3) * 256 + g] = 0.505f * acc3 + bb;
  } else {
    Sb[(size_t)(nr0 + 0) * 256 + g] = 0.505f * acc0;
    Sb[(size_t)(nr0 + 1) * 256 + g] = 0.505f * acc1;
    Sb[(size_t)(nr0 + 2) * 256 + g] = 0.505f * acc2;
    Sb[(size_t)(nr0 + 3) * 256 + g] = 0.505f * acc3;
  }
}

// ---------------------------------------------------------------------------
// Main fused kernel. Tiny LDS for the per-iter cross-wave g-reduction.
// ---------------------------------------------------------------------------
__global__ __launch_bounds__(512, 2) void fused_main(
    const _Float16* __restrict__ upack, const _Float16* __restrict__ vpack,
    const _Float16* __restrict__ w1pk,
    const float* __restrict__ Ra, const float* __restrict__ Sb,
    const float* __restrict__ w2, const float* __restrict__ b2,
    float* __restrict__ out) {
  __shared__ float lds_p[2][8][32];
  int bid = blockIdx.x;             // n(3b) | bblk(3b) | aq(2b)
  int n = bid >> 5;
  int bblk = (bid >> 2) & 7;
  int aq = bid & 3;
  int tid = threadIdx.x;
  int ws = tid >> 6;                // wave id = g-tile (32 g each)
  int l = tid & 63;
  int l31 = l & 31, lh = l >> 5;

  // Stationary 0.495*w1 A-fragments for gt=ws: 64 regs.
  f16x8 w1f[16];
#pragma unroll
  for (int kt = 0; kt < 16; ++kt)
    w1f[kt] = *reinterpret_cast<const f16x8*>(w1pk + ((kt * 8 + ws) * 64 + l) * 8);

  // Stationary v B-fragments for this (n,bblk): 64 regs.
  const _Float16* vbase = vpack + (size_t)((n * 8 + bblk) * 16) * 512 + l * 8;
  f16x8 vf[16];
#pragma unroll
  for (int kt = 0; kt < 16; ++kt)
    vf[kt] = *reinterpret_cast<const f16x8*>(vbase + kt * 512);

  // Per-lane constants; C/D layout: reg r -> row g = ws*32 + 8*(r>>2) + 4*lh + (r&3),
  // col b = l31.  Sb row for this lane: n*256 + bblk*32 + l31.
  float sbf[16], w2f[16];
  const float* sbrow = Sb + (size_t)(n * 256 + bblk * 32 + l31) * 256;
#pragma unroll
  for (int rg = 0; rg < 4; ++rg) {
    int gbase = ws * 32 + 8 * rg + 4 * lh;
    float4 ss = *reinterpret_cast<const float4*>(sbrow + gbase);
    float4 ww = *reinterpret_cast<const float4*>(w2 + gbase);
    sbf[4 * rg + 0] = ss.x; sbf[4 * rg + 1] = ss.y;
    sbf[4 * rg + 2] = ss.z; sbf[4 * rg + 3] = ss.w;
    w2f[4 * rg + 0] = ww.x; w2f[4 * rg + 1] = ww.y;
    w2f[4 * rg + 2] = ww.z; w2f[4 * rg + 3] = ww.w;
  }
  float b2v = b2[0];

  const _Float16* ub = upack + (size_t)(n * 256 + aq * 64) * 256 + lh * 8;
  const float* rabase = Ra + (size_t)(n * 256 + aq * 64) * 256;

  for (int it = 0; it < 64; ++it) {
    const _Float16* ur = ub + (size_t)it * 256;
    const float* rar = rabase + (size_t)it * 256;

    // C-init: accA = 0.505(P-Q) + b1 in C/D layout; accB = 0.
    f32x16 accA, accB;
#pragma unroll
    for (int rg = 0; rg < 4; ++rg) {
      float4 rr = *reinterpret_cast<const float4*>(rar + ws * 32 + 8 * rg + 4 * lh);
      accA[4 * rg + 0] = rr.x - sbf[4 * rg + 0];
      accA[4 * rg + 1] = rr.y - sbf[4 * rg + 1];
      accA[4 * rg + 2] = rr.z - sbf[4 * rg + 2];
      accA[4 * rg + 3] = rr.w - sbf[4 * rg + 3];
    }
#pragma unroll
    for (int r = 0; r < 16; ++r) accB[r] = 0.f;

#pragma unroll
    for (int kt = 0; kt < 16; ++kt) {
      f16x8 uu = *reinterpret_cast<const f16x8*>(ur + kt * 16);
      f16x8 d = uu - vf[kt];                       // 4x v_pk_add_f16
      i32x4 di = __builtin_bit_cast(i32x4, d);
      di &= 0x7fff7fff;                            // 4x v_and_b32 -> |d|
      f16x8 ad = __builtin_bit_cast(f16x8, di);
      if (kt & 1)
        accB = __builtin_amdgcn_mfma_f32_32x32x16_f16(w1f[kt], ad, accB, 0, 0, 0);
      else
        accA = __builtin_amdgcn_mfma_f32_32x32x16_f16(w1f[kt], ad, accA, 0, 0, 0);
    }

    // hidden1 = leaky(accA+accB); partial p = hidden1 . w2 (16 g in-lane)
    float p = 0.f;
#pragma unroll
    for (int r = 0; r < 16; ++r) {
      float s = accA[r] + accB[r];
      float h = fmaxf(s, 0.01f * s);
      p = fmaf(h, w2f[r], p);
    }
    p += __shfl_xor(p, 32, 64);     // fold the two lh halves (g split by lh)

    int ph = it & 1;
    if (l < 32) lds_p[ph][ws][l] = p;
    __syncthreads();
    if (ws == 0 && l < 32) {
      float s = b2v;
#pragma unroll
      for (int w = 0; w < 8; ++w) s += lds_p[ph][w][l];
      int a = aq * 64 + it;
      out[(size_t)(n * 256 + a) * 256 + bblk * 32 + l] = 1.f / (1.f + __expf(-s));
    }
    // ping-pong: next iter writes the other buffer; one barrier per iter
  }
}

extern "C" void kernel_launch(void* const* d_in, const int* in_sizes, int n_in,
                              void* d_out, int out_size, void* d_ws, size_t ws_size,
                              hipStream_t stream) {
  const float* za = (const float*)d_in[0];
  const float* zb = (const float*)d_in[1];
  const float* w0 = (const float*)d_in[2];
  const float* b0 = (const float*)d_in[3];
  const float* w1 = (const float*)d_in[4];
  const float* b1 = (const float*)d_in[5];
  const float* w2 = (const float*)d_in[6];
  const float* b2 = (const float*)d_in[7];
  float* out = (float*)d_out;

  char* ws = (char*)d_ws;
  _Float16* upack = (_Float16*)ws;                        // 1 MB @ 0
  _Float16* vpack = (_Float16*)(ws + (1u << 20));         // 1 MB @ 1M
  _Float16* vlin  = (_Float16*)(ws + (2u << 20));         // 1 MB @ 2M
  _Float16* w1pk  = (_Float16*)(ws + (3u << 20));         // 128 KB @ 3M
  float*    Ra    = (float*)(ws + (7u << 19));            // 2 MB @ 3.5M
  float*    Sb    = (float*)(ws + (11u << 19));           // 2 MB @ 5.5M

  pack_all<<<2304, 256, 0, stream>>>(za, zb, w0, b0, w1, upack, vpack, vlin, w1pk);
  pq_kernel<<<1024, 256, 0, stream>>>(upack, vlin, w1, b1, Ra, Sb);
  fused_main<<<256, 512, 0, stream>>>(upack, vpack, w1pk, Ra, Sb, w2, b2, out);
}

// Round 10
// 177.694 us; speedup vs baseline: 1.1032x; 1.1032x over previous
//
#include <hip/hip_runtime.h>
#include <hip/hip_fp16.h>

// out[n,a,b] = sigmoid(w2 . leaky(w1 . leaky(u'[n,a,:] - v[n,b,:]) + b1) + b2)
// u' = za.w0^T + b0, v = zb.w0^T (precomputed f16).
// Algebra: leaky(x) = 0.505x + 0.495|x|, so
//   w1.leaky(u-v) + b1 = [0.505(P[a,g]-Q[b,g]) + b1[g]] + (0.495 w1).|u-v|
// with P = u'.w1^T, Q = v.w1^T precomputed from the SAME f16-rounded u,v.
// Main GEMM: A = 0.495*w1 stationary in regs (wave's 32-g tile), B = |u-v|
// built with pk_sub + and-mask; affine part folded into MFMA C-init.
// MODE 0 (ws big enough): NO barriers/LDS in main loop; per-wave partial p
//   written to global pws; tiny reduce kernel sums 8 waves + sigmoid.
// MODE 1 (fallback): in-kernel LDS reduce batched to 1 barrier / 4 iters.

typedef float f32x16 __attribute__((ext_vector_type(16)));
typedef _Float16 f16x8 __attribute__((ext_vector_type(8)));
typedef int i32x4 __attribute__((ext_vector_type(4)));

// ---------------------------------------------------------------------------
// Merged pack kernel.
// Blocks 0..2047: u' (f16 linear), v (f16 B-frag-linear), v (f16 linear).
// Blocks 2048..2303: 0.495*w1 into A-frag-linear f16.
// ---------------------------------------------------------------------------
__global__ __launch_bounds__(256) void pack_all(
    const float* __restrict__ za, const float* __restrict__ zb,
    const float* __restrict__ w0, const float* __restrict__ b0,
    const float* __restrict__ w1,
    _Float16* __restrict__ upack, _Float16* __restrict__ vpack,
    _Float16* __restrict__ vlin, _Float16* __restrict__ w1pk) {
  int bid = blockIdx.x;
  int tid = threadIdx.x;
  if (bid < 2048) {
    int nr = bid;                   // n*256 + r
    int n = nr >> 8, r = nr & 255;
    __shared__ float arow[64], brow[64];
    if (tid < 64) arow[tid] = za[nr * 64 + tid];
    else if (tid < 128) brow[tid - 64] = zb[nr * 64 + (tid - 64)];
    __syncthreads();
    int h = tid;
    const float* w0r = w0 + h * 64;
    float ua = 0.f, vb = 0.f;
#pragma unroll
    for (int c = 0; c < 64; c += 4) {
      float4 w = *reinterpret_cast<const float4*>(w0r + c);
      ua += w.x * arow[c] + w.y * arow[c + 1] + w.z * arow[c + 2] + w.w * arow[c + 3];
      vb += w.x * brow[c] + w.y * brow[c + 1] + w.z * brow[c + 2] + w.w * brow[c + 3];
    }
    upack[nr * 256 + h] = (_Float16)(ua + b0[h]);
    _Float16 vh = (_Float16)vb;
    vlin[nr * 256 + h] = vh;
    // v B-frag-linear: frag (n, bblk=r>>5, kiter=h>>4); lane = lh*32 + (r&31)
    int bblk = r >> 5, lcol = r & 31;
    int kiter = h >> 4, rem = h & 15, lh = rem >> 3, j = rem & 7;
    int lane = lh * 32 + lcol;
    vpack[(((n * 8 + bblk) * 16 + kiter) * 64 + lane) * 8 + j] = vh;
  } else {
    int id = (bid - 2048) * 256 + tid;   // 0..65535
    int g = id >> 8, k = id & 255;
    int gt = g >> 5, lcol = g & 31;
    int kiter = k >> 4, rem = k & 15, lh = rem >> 3, j = rem & 7;
    int lane = lh * 32 + lcol;
    w1pk[((kiter * 8 + gt) * 64 + lane) * 8 + j] = (_Float16)(0.495f * w1[id]);
  }
}

// ---------------------------------------------------------------------------
// P/Q precompute: Ra[nr,g] = 0.505*sum_k w1[g,k]*u'[nr,k] + b1[g]
//                 Sb[nr,g] = 0.505*sum_k w1[g,k]*v[nr,k]
// ---------------------------------------------------------------------------
__global__ __launch_bounds__(256) void pq_kernel(
    const _Float16* __restrict__ upack, const _Float16* __restrict__ vlin,
    const float* __restrict__ w1, const float* __restrict__ b1,
    float* __restrict__ Ra, float* __restrict__ Sb) {
  int bid = blockIdx.x;
  int which = bid >> 9;
  int nr0 = (bid & 511) * 4;
  __shared__ float rows[4][256];
  int tid = threadIdx.x;
  const _Float16* src = which ? vlin : upack;
#pragma unroll
  for (int i = 0; i < 4; ++i)
    rows[i][tid] = (float)src[(size_t)(nr0 + i) * 256 + tid];
  __syncthreads();
  int g = tid;
  const float* w1r = w1 + (size_t)g * 256;
  float acc0 = 0.f, acc1 = 0.f, acc2 = 0.f, acc3 = 0.f;
#pragma unroll 8
  for (int k = 0; k < 256; k += 4) {
    float4 w = *reinterpret_cast<const float4*>(w1r + k);
    acc0 += w.x * rows[0][k] + w.y * rows[0][k + 1] + w.z * rows[0][k + 2] + w.w * rows[0][k + 3];
    acc1 += w.x * rows[1][k] + w.y * rows[1][k + 1] + w.z * rows[1][k + 2] + w.w * rows[1][k + 3];
    acc2 += w.x * rows[2][k] + w.y * rows[2][k + 1] + w.z * rows[2][k + 2] + w.w * rows[2][k + 3];
    acc3 += w.x * rows[3][k] + w.y * rows[3][k + 1] + w.z * rows[3][k + 2] + w.w * rows[3][k + 3];
  }
  if (which == 0) {
    float bb = b1[g];
    Ra[(size_t)(nr0 + 0) * 256 + g] = 0.505f * acc0 + bb;
    Ra[(size_t)(nr0 + 1) * 256 + g] = 0.505f * acc1 + bb;
    Ra[(size_t)(nr0 + 2) * 256 + g] = 0.505f * acc2 + bb;
    Ra[(size_t)(nr0 + 3) * 256 + g] = 0.505f * acc3 + bb;
  } else {
    Sb[(size_t)(nr0 + 0) * 256 + g] = 0.505f * acc0;
    Sb[(size_t)(nr0 + 1) * 256 + g] = 0.505f * acc1;
    Sb[(size_t)(nr0 + 2) * 256 + g] = 0.505f * acc2;
    Sb[(size_t)(nr0 + 3) * 256 + g] = 0.505f * acc3;
  }
}

// ---------------------------------------------------------------------------
// Main fused kernel.
// MODE 0: barrier-free; per-wave partials to pws (global).
// MODE 1: LDS reduce, 1 barrier per 4 a-iters.
// ---------------------------------------------------------------------------
template <int MODE>
__global__ __launch_bounds__(512, 2) void fused_main(
    const _Float16* __restrict__ upack, const _Float16* __restrict__ vpack,
    const _Float16* __restrict__ w1pk,
    const float* __restrict__ Ra, const float* __restrict__ Sb,
    const float* __restrict__ w2, const float* __restrict__ b2,
    float* __restrict__ pws, float* __restrict__ out) {
  int bid = blockIdx.x;             // n(3b) | bblk(3b) | aq(2b)
  int n = bid >> 5;
  int bblk = (bid >> 2) & 7;
  int aq = bid & 3;
  int tid = threadIdx.x;
  int ws = tid >> 6;                // wave id = g-tile (32 g each)
  int l = tid & 63;
  int l31 = l & 31, lh = l >> 5;

  // Stationary 0.495*w1 A-fragments for gt=ws: 64 regs.
  f16x8 w1f[16];
#pragma unroll
  for (int kt = 0; kt < 16; ++kt)
    w1f[kt] = *reinterpret_cast<const f16x8*>(w1pk + ((kt * 8 + ws) * 64 + l) * 8);

  // Stationary v B-fragments for this (n,bblk): 64 regs.
  const _Float16* vbase = vpack + (size_t)((n * 8 + bblk) * 16) * 512 + l * 8;
  f16x8 vf[16];
#pragma unroll
  for (int kt = 0; kt < 16; ++kt)
    vf[kt] = *reinterpret_cast<const f16x8*>(vbase + kt * 512);

  // Per-lane constants; C/D layout: reg r -> row g = ws*32 + 8*(r>>2) + 4*lh + (r&3),
  // col b = l31.  Sb row for this lane: n*256 + bblk*32 + l31.
  float sbf[16], w2f[16];
  const float* sbrow = Sb + (size_t)(n * 256 + bblk * 32 + l31) * 256;
#pragma unroll
  for (int rg = 0; rg < 4; ++rg) {
    int gbase = ws * 32 + 8 * rg + 4 * lh;
    float4 ss = *reinterpret_cast<const float4*>(sbrow + gbase);
    float4 ww = *reinterpret_cast<const float4*>(w2 + gbase);
    sbf[4 * rg + 0] = ss.x; sbf[4 * rg + 1] = ss.y;
    sbf[4 * rg + 2] = ss.z; sbf[4 * rg + 3] = ss.w;
    w2f[4 * rg + 0] = ww.x; w2f[4 * rg + 1] = ww.y;
    w2f[4 * rg + 2] = ww.z; w2f[4 * rg + 3] = ww.w;
  }
  float b2v = b2[0];

  const _Float16* ub = upack + (size_t)(n * 256 + aq * 64) * 256 + lh * 8;
  const float* rabase = Ra + (size_t)(n * 256 + aq * 64) * 256;

  if constexpr (MODE == 0) {
    // -------- barrier-free: partials to global, reduce kernel finishes -----
    float* pw = pws + ((size_t)bid * 64 * 8 + ws) * 32;
    for (int it = 0; it < 64; ++it) {
      const _Float16* ur = ub + (size_t)it * 256;
      const float* rar = rabase + (size_t)it * 256;

      f32x16 accA, accB;
#pragma unroll
      for (int rg = 0; rg < 4; ++rg) {
        float4 rr = *reinterpret_cast<const float4*>(rar + ws * 32 + 8 * rg + 4 * lh);
        accA[4 * rg + 0] = rr.x - sbf[4 * rg + 0];
        accA[4 * rg + 1] = rr.y - sbf[4 * rg + 1];
        accA[4 * rg + 2] = rr.z - sbf[4 * rg + 2];
        accA[4 * rg + 3] = rr.w - sbf[4 * rg + 3];
      }
#pragma unroll
      for (int r = 0; r < 16; ++r) accB[r] = 0.f;

#pragma unroll
      for (int kt = 0; kt < 16; ++kt) {
        f16x8 uu = *reinterpret_cast<const f16x8*>(ur + kt * 16);
        f16x8 d = uu - vf[kt];
        i32x4 di = __builtin_bit_cast(i32x4, d);
        di &= 0x7fff7fff;                          // |d|
        f16x8 ad = __builtin_bit_cast(f16x8, di);
        if (kt & 1)
          accB = __builtin_amdgcn_mfma_f32_32x32x16_f16(w1f[kt], ad, accB, 0, 0, 0);
        else
          accA = __builtin_amdgcn_mfma_f32_32x32x16_f16(w1f[kt], ad, accA, 0, 0, 0);
      }

      float p = 0.f;
#pragma unroll
      for (int r = 0; r < 16; ++r) {
        float s = accA[r] + accB[r];
        float h = fmaxf(s, 0.01f * s);
        p = fmaf(h, w2f[r], p);
      }
      p += __shfl_xor(p, 32, 64);   // intra-wave: no barrier needed
      if (l < 32) pw[(size_t)it * 256 + l31] = p;   // it*8*32 floats per iter
    }
  } else {
    // -------- fallback: LDS reduce, 1 barrier per 4 iters ------------------
    __shared__ float lds_p[2][4][8][32];
    for (int bt = 0; bt < 16; ++bt) {
      int ph = bt & 1;
      for (int j = 0; j < 4; ++j) {
        int it = bt * 4 + j;
        const _Float16* ur = ub + (size_t)it * 256;
        const float* rar = rabase + (size_t)it * 256;

        f32x16 accA, accB;
#pragma unroll
        for (int rg = 0; rg < 4; ++rg) {
          float4 rr = *reinterpret_cast<const float4*>(rar + ws * 32 + 8 * rg + 4 * lh);
          accA[4 * rg + 0] = rr.x - sbf[4 * rg + 0];
          accA[4 * rg + 1] = rr.y - sbf[4 * rg + 1];
          accA[4 * rg + 2] = rr.z - sbf[4 * rg + 2];
          accA[4 * rg + 3] = rr.w - sbf[4 * rg + 3];
        }
#pragma unroll
        for (int r = 0; r < 16; ++r) accB[r] = 0.f;

#pragma unroll
        for (int kt = 0; kt < 16; ++kt) {
          f16x8 uu = *reinterpret_cast<const f16x8*>(ur + kt * 16);
          f16x8 d = uu - vf[kt];
          i32x4 di = __builtin_bit_cast(i32x4, d);
          di &= 0x7fff7fff;
          f16x8 ad = __builtin_bit_cast(f16x8, di);
          if (kt & 1)
            accB = __builtin_amdgcn_mfma_f32_32x32x16_f16(w1f[kt], ad, accB, 0, 0, 0);
          else
            accA = __builtin_amdgcn_mfma_f32_32x32x16_f16(w1f[kt], ad, accA, 0, 0, 0);
        }

        float p = 0.f;
#pragma unroll
        for (int r = 0; r < 16; ++r) {
          float s = accA[r] + accB[r];
          float h = fmaxf(s, 0.01f * s);
          p = fmaf(h, w2f[r], p);
        }
        p += __shfl_xor(p, 32, 64);
        if (l < 32) lds_p[ph][j][ws][l31] = p;
      }
      __syncthreads();
      if (tid < 128) {
        int al = tid >> 5, b = tid & 31;
        float s = b2v;
#pragma unroll
        for (int w = 0; w < 8; ++w) s += lds_p[ph][al][w][b];
        int a = aq * 64 + bt * 4 + al;
        out[(size_t)(n * 256 + a) * 256 + bblk * 32 + b] = 1.f / (1.f + __expf(-s));
      }
    }
  }
}

// ---------------------------------------------------------------------------
// Reduce kernel (MODE 0 only): out = sigmoid(sum_8 pws + b2).
// ---------------------------------------------------------------------------
__global__ __launch_bounds__(256) void reduce_kernel(
    const float* __restrict__ pws, const float* __restrict__ b2,
    float* __restrict__ out) {
  int o = blockIdx.x * 256 + threadIdx.x;     // (n,a,b) flat
  int n = o >> 16, a = (o >> 8) & 255, b = o & 255;
  int bblk = b >> 5, b32 = b & 31, aq = a >> 6, it = a & 63;
  int mbid = (n << 5) | (bblk << 2) | aq;
  const float* p = pws + (((size_t)mbid * 64 + it) * 8) * 32 + b32;
  float s = b2[0];
#pragma unroll
  for (int w = 0; w < 8; ++w) s += p[w * 32];
  out[o] = 1.f / (1.f + __expf(-s));
}

extern "C" void kernel_launch(void* const* d_in, const int* in_sizes, int n_in,
                              void* d_out, int out_size, void* d_ws, size_t ws_size,
                              hipStream_t stream) {
  const float* za = (const float*)d_in[0];
  const float* zb = (const float*)d_in[1];
  const float* w0 = (const float*)d_in[2];
  const float* b0 = (const float*)d_in[3];
  const float* w1 = (const float*)d_in[4];
  const float* b1 = (const float*)d_in[5];
  const float* w2 = (const float*)d_in[6];
  const float* b2 = (const float*)d_in[7];
  float* out = (float*)d_out;

  char* ws = (char*)d_ws;
  _Float16* upack = (_Float16*)ws;                        // 1 MB @ 0
  _Float16* vpack = (_Float16*)(ws + (1u << 20));         // 1 MB @ 1M
  _Float16* vlin  = (_Float16*)(ws + (2u << 20));         // 1 MB @ 2M
  _Float16* w1pk  = (_Float16*)(ws + (3u << 20));         // 128 KB @ 3M
  float*    Ra    = (float*)(ws + (7u << 19));            // 2 MB @ 3.5M
  float*    Sb    = (float*)(ws + (11u << 19));           // 2 MB @ 5.5M
  float*    pws   = (float*)(ws + (15u << 19));           // 16 MB @ 7.5M

  pack_all<<<2304, 256, 0, stream>>>(za, zb, w0, b0, w1, upack, vpack, vlin, w1pk);
  pq_kernel<<<1024, 256, 0, stream>>>(upack, vlin, w1, b1, Ra, Sb);

  const size_t need = (15ull << 19) + 256ull * 64 * 8 * 32 * 4;  // 24.25 MB
  if (ws_size >= need) {
    fused_main<0><<<256, 512, 0, stream>>>(upack, vpack, w1pk, Ra, Sb, w2, b2, pws, out);
    reduce_kernel<<<2048, 256, 0, stream>>>(pws, b2, out);
  } else {
    fused_main<1><<<256, 512, 0, stream>>>(upack, vpack, w1pk, Ra, Sb, w2, b2, nullptr, out);
  }
}

// Round 11
// 169.369 us; speedup vs baseline: 1.1575x; 1.0492x over previous
//
#include <hip/hip_runtime.h>
#include <hip/hip_fp16.h>

// out[n,a,b] = sigmoid(w2 . leaky(w1 . leaky(u'[n,a,:] - v[n,b,:]) + b1) + b2)
// u' = za.w0^T + b0, v = zb.w0^T (precomputed f16).
// Algebra: leaky(x) = 0.505x + 0.495|x|, so
//   w1.leaky(u-v) + b1 = [0.505(P[a,g]-Q[b,g]) + b1[g]] + (0.495 w1).|u-v|
// with P = u'.w1^T, Q = v.w1^T precomputed from the SAME f16-rounded u,v.
// Main GEMM: A = 0.495*w1 stationary in regs (wave's 32-g tile), B = |u-v|
// built with pk_sub + and-mask; affine part folded into MFMA C-init.
// R11: 2 a-iterations processed per loop pass (2 independent acc chains,
// interleaved MFMAs, shared stationaries) + tree-reduced epilogue — targets
// the ~50% dependency-stall fraction seen in R10 counters.
// MODE 0: no barriers/LDS in main loop; partials to pws; reduce kernel sums.
// MODE 1 (fallback, small ws): in-kernel LDS reduce.

typedef float f32x16 __attribute__((ext_vector_type(16)));
typedef _Float16 f16x8 __attribute__((ext_vector_type(8)));
typedef int i32x4 __attribute__((ext_vector_type(4)));

// ---------------------------------------------------------------------------
// Merged pack kernel.
// Blocks 0..2047: u' (f16 linear), v (f16 B-frag-linear), v (f16 linear).
// Blocks 2048..2303: 0.495*w1 into A-frag-linear f16.
// ---------------------------------------------------------------------------
__global__ __launch_bounds__(256) void pack_all(
    const float* __restrict__ za, const float* __restrict__ zb,
    const float* __restrict__ w0, const float* __restrict__ b0,
    const float* __restrict__ w1,
    _Float16* __restrict__ upack, _Float16* __restrict__ vpack,
    _Float16* __restrict__ vlin, _Float16* __restrict__ w1pk) {
  int bid = blockIdx.x;
  int tid = threadIdx.x;
  if (bid < 2048) {
    int nr = bid;                   // n*256 + r
    int n = nr >> 8, r = nr & 255;
    __shared__ float arow[64], brow[64];
    if (tid < 64) arow[tid] = za[nr * 64 + tid];
    else if (tid < 128) brow[tid - 64] = zb[nr * 64 + (tid - 64)];
    __syncthreads();
    int h = tid;
    const float* w0r = w0 + h * 64;
    float ua = 0.f, vb = 0.f;
#pragma unroll
    for (int c = 0; c < 64; c += 4) {
      float4 w = *reinterpret_cast<const float4*>(w0r + c);
      ua += w.x * arow[c] + w.y * arow[c + 1] + w.z * arow[c + 2] + w.w * arow[c + 3];
      vb += w.x * brow[c] + w.y * brow[c + 1] + w.z * brow[c + 2] + w.w * brow[c + 3];
    }
    upack[nr * 256 + h] = (_Float16)(ua + b0[h]);
    _Float16 vh = (_Float16)vb;
    vlin[nr * 256 + h] = vh;
    // v B-frag-linear: frag (n, bblk=r>>5, kiter=h>>4); lane = lh*32 + (r&31)
    int bblk = r >> 5, lcol = r & 31;
    int kiter = h >> 4, rem = h & 15, lh = rem >> 3, j = rem & 7;
    int lane = lh * 32 + lcol;
    vpack[(((n * 8 + bblk) * 16 + kiter) * 64 + lane) * 8 + j] = vh;
  } else {
    int id = (bid - 2048) * 256 + tid;   // 0..65535
    int g = id >> 8, k = id & 255;
    int gt = g >> 5, lcol = g & 31;
    int kiter = k >> 4, rem = k & 15, lh = rem >> 3, j = rem & 7;
    int lane = lh * 32 + lcol;
    w1pk[((kiter * 8 + gt) * 64 + lane) * 8 + j] = (_Float16)(0.495f * w1[id]);
  }
}

// ---------------------------------------------------------------------------
// P/Q precompute: Ra[nr,g] = 0.505*sum_k w1[g,k]*u'[nr,k] + b1[g]
//                 Sb[nr,g] = 0.505*sum_k w1[g,k]*v[nr,k]
// ---------------------------------------------------------------------------
__global__ __launch_bounds__(256) void pq_kernel(
    const _Float16* __restrict__ upack, const _Float16* __restrict__ vlin,
    const float* __restrict__ w1, const float* __restrict__ b1,
    float* __restrict__ Ra, float* __restrict__ Sb) {
  int bid = blockIdx.x;
  int which = bid >> 9;
  int nr0 = (bid & 511) * 4;
  __shared__ float rows[4][256];
  int tid = threadIdx.x;
  const _Float16* src = which ? vlin : upack;
#pragma unroll
  for (int i = 0; i < 4; ++i)
    rows[i][tid] = (float)src[(size_t)(nr0 + i) * 256 + tid];
  __syncthreads();
  int g = tid;
  const float* w1r = w1 + (size_t)g * 256;
  float acc0 = 0.f, acc1 = 0.f, acc2 = 0.f, acc3 = 0.f;
#pragma unroll 8
  for (int k = 0; k < 256; k += 4) {
    float4 w = *reinterpret_cast<const float4*>(w1r + k);
    acc0 += w.x * rows[0][k] + w.y * rows[0][k + 1] + w.z * rows[0][k + 2] + w.w * rows[0][k + 3];
    acc1 += w.x * rows[1][k] + w.y * rows[1][k + 1] + w.z * rows[1][k + 2] + w.w * rows[1][k + 3];
    acc2 += w.x * rows[2][k] + w.y * rows[2][k + 1] + w.z * rows[2][k + 2] + w.w * rows[2][k + 3];
    acc3 += w.x * rows[3][k] + w.y * rows[3][k + 1] + w.z * rows[3][k + 2] + w.w * rows[3][k + 3];
  }
  if (which == 0) {
    float bb = b1[g];
    Ra[(size_t)(nr0 + 0) * 256 + g] = 0.505f * acc0 + bb;
    Ra[(size_t)(nr0 + 1) * 256 + g] = 0.505f * acc1 + bb;
    Ra[(size_t)(nr0 + 2) * 256 + g] = 0.505f * acc2 + bb;
    Ra[(size_t)(nr0 + 3) * 256 + g] = 0.505f * acc3 + bb;
  } else {
    Sb[(size_t)(nr0 + 0) * 256 + g] = 0.505f * acc0;
    Sb[(size_t)(nr0 + 1) * 256 + g] = 0.505f * acc1;
    Sb[(size_t)(nr0 + 2) * 256 + g] = 0.505f * acc2;
    Sb[(size_t)(nr0 + 3) * 256 + g] = 0.505f * acc3;
  }
}

// ---------------------------------------------------------------------------
// Main fused kernel.
// ---------------------------------------------------------------------------
template <int MODE>
__global__ __launch_bounds__(512, 2) void fused_main(
    const _Float16* __restrict__ upack, const _Float16* __restrict__ vpack,
    const _Float16* __restrict__ w1pk,
    const float* __restrict__ Ra, const float* __restrict__ Sb,
    const float* __restrict__ w2, const float* __restrict__ b2,
    float* __restrict__ pws, float* __restrict__ out) {
  int bid = blockIdx.x;             // n(3b) | bblk(3b) | aq(2b)
  int n = bid >> 5;
  int bblk = (bid >> 2) & 7;
  int aq = bid & 3;
  int tid = threadIdx.x;
  int ws = tid >> 6;                // wave id = g-tile (32 g each)
  int l = tid & 63;
  int l31 = l & 31, lh = l >> 5;

  // Stationary 0.495*w1 A-fragments for gt=ws: 64 regs.
  f16x8 w1f[16];
#pragma unroll
  for (int kt = 0; kt < 16; ++kt)
    w1f[kt] = *reinterpret_cast<const f16x8*>(w1pk + ((kt * 8 + ws) * 64 + l) * 8);

  // Stationary v B-fragments for this (n,bblk): 64 regs.
  const _Float16* vbase = vpack + (size_t)((n * 8 + bblk) * 16) * 512 + l * 8;
  f16x8 vf[16];
#pragma unroll
  for (int kt = 0; kt < 16; ++kt)
    vf[kt] = *reinterpret_cast<const f16x8*>(vbase + kt * 512);

  // Per-lane constants; C/D layout: reg r -> row g = ws*32 + 8*(r>>2) + 4*lh + (r&3),
  // col b = l31.  Sb row for this lane: n*256 + bblk*32 + l31.
  float sbf[16], w2f[16];
  const float* sbrow = Sb + (size_t)(n * 256 + bblk * 32 + l31) * 256;
#pragma unroll
  for (int rg = 0; rg < 4; ++rg) {
    int gbase = ws * 32 + 8 * rg + 4 * lh;
    float4 ss = *reinterpret_cast<const float4*>(sbrow + gbase);
    float4 ww = *reinterpret_cast<const float4*>(w2 + gbase);
    sbf[4 * rg + 0] = ss.x; sbf[4 * rg + 1] = ss.y;
    sbf[4 * rg + 2] = ss.z; sbf[4 * rg + 3] = ss.w;
    w2f[4 * rg + 0] = ww.x; w2f[4 * rg + 1] = ww.y;
    w2f[4 * rg + 2] = ww.z; w2f[4 * rg + 3] = ww.w;
  }
  float b2v = b2[0];

  const _Float16* ub = upack + (size_t)(n * 256 + aq * 64) * 256 + lh * 8;
  const float* rabase = Ra + (size_t)(n * 256 + aq * 64) * 256;

  if constexpr (MODE == 0) {
    float* pw = pws + ((size_t)bid * 64 * 8 + ws) * 32;
    // 2 a-iterations per pass: independent acc chains, shared stationaries.
    for (int it = 0; it < 64; it += 2) {
      const _Float16* ur0 = ub + (size_t)it * 256;
      const _Float16* ur1 = ur0 + 256;
      const float* rar0 = rabase + (size_t)it * 256;
      const float* rar1 = rar0 + 256;

      // C-init both iters (Ra - Sb, C/D layout).
      f32x16 acc0, acc1;
#pragma unroll
      for (int rg = 0; rg < 4; ++rg) {
        float4 r0 = *reinterpret_cast<const float4*>(rar0 + ws * 32 + 8 * rg + 4 * lh);
        float4 r1 = *reinterpret_cast<const float4*>(rar1 + ws * 32 + 8 * rg + 4 * lh);
        acc0[4 * rg + 0] = r0.x - sbf[4 * rg + 0];
        acc0[4 * rg + 1] = r0.y - sbf[4 * rg + 1];
        acc0[4 * rg + 2] = r0.z - sbf[4 * rg + 2];
        acc0[4 * rg + 3] = r0.w - sbf[4 * rg + 3];
        acc1[4 * rg + 0] = r1.x - sbf[4 * rg + 0];
        acc1[4 * rg + 1] = r1.y - sbf[4 * rg + 1];
        acc1[4 * rg + 2] = r1.z - sbf[4 * rg + 2];
        acc1[4 * rg + 3] = r1.w - sbf[4 * rg + 3];
      }

#pragma unroll
      for (int kt = 0; kt < 16; ++kt) {
        f16x8 u0 = *reinterpret_cast<const f16x8*>(ur0 + kt * 16);
        f16x8 u1 = *reinterpret_cast<const f16x8*>(ur1 + kt * 16);
        f16x8 d0 = u0 - vf[kt];
        f16x8 d1 = u1 - vf[kt];
        i32x4 i0 = __builtin_bit_cast(i32x4, d0); i0 &= 0x7fff7fff;
        i32x4 i1 = __builtin_bit_cast(i32x4, d1); i1 &= 0x7fff7fff;
        acc0 = __builtin_amdgcn_mfma_f32_32x32x16_f16(
            w1f[kt], __builtin_bit_cast(f16x8, i0), acc0, 0, 0, 0);
        acc1 = __builtin_amdgcn_mfma_f32_32x32x16_f16(
            w1f[kt], __builtin_bit_cast(f16x8, i1), acc1, 0, 0, 0);
      }

      // Epilogue both iters, tree-reduced (4 partial chains of 4 + combine).
      float q00 = 0.f, q01 = 0.f, q02 = 0.f, q03 = 0.f;
      float q10 = 0.f, q11 = 0.f, q12 = 0.f, q13 = 0.f;
#pragma unroll
      for (int rg = 0; rg < 4; ++rg) {
        float h;
        h = acc0[4 * rg + 0]; h = fmaxf(h, 0.01f * h); q00 = fmaf(h, w2f[4 * rg + 0], q00);
        h = acc0[4 * rg + 1]; h = fmaxf(h, 0.01f * h); q01 = fmaf(h, w2f[4 * rg + 1], q01);
        h = acc0[4 * rg + 2]; h = fmaxf(h, 0.01f * h); q02 = fmaf(h, w2f[4 * rg + 2], q02);
        h = acc0[4 * rg + 3]; h = fmaxf(h, 0.01f * h); q03 = fmaf(h, w2f[4 * rg + 3], q03);
        h = acc1[4 * rg + 0]; h = fmaxf(h, 0.01f * h); q10 = fmaf(h, w2f[4 * rg + 0], q10);
        h = acc1[4 * rg + 1]; h = fmaxf(h, 0.01f * h); q11 = fmaf(h, w2f[4 * rg + 1], q11);
        h = acc1[4 * rg + 2]; h = fmaxf(h, 0.01f * h); q12 = fmaf(h, w2f[4 * rg + 2], q12);
        h = acc1[4 * rg + 3]; h = fmaxf(h, 0.01f * h); q13 = fmaf(h, w2f[4 * rg + 3], q13);
      }
      float p0 = (q00 + q01) + (q02 + q03);
      float p1 = (q10 + q11) + (q12 + q13);
      p0 += __shfl_xor(p0, 32, 64);
      p1 += __shfl_xor(p1, 32, 64);
      if (l < 32) {
        pw[(size_t)it * 256 + l31] = p0;
        pw[(size_t)(it + 1) * 256 + l31] = p1;
      }
    }
  } else {
    // -------- fallback: LDS reduce, 1 barrier per 4 iters ------------------
    __shared__ float lds_p[2][4][8][32];
    for (int bt = 0; bt < 16; ++bt) {
      int ph = bt & 1;
      for (int j = 0; j < 4; ++j) {
        int it = bt * 4 + j;
        const _Float16* ur = ub + (size_t)it * 256;
        const float* rar = rabase + (size_t)it * 256;

        f32x16 accA;
#pragma unroll
        for (int rg = 0; rg < 4; ++rg) {
          float4 rr = *reinterpret_cast<const float4*>(rar + ws * 32 + 8 * rg + 4 * lh);
          accA[4 * rg + 0] = rr.x - sbf[4 * rg + 0];
          accA[4 * rg + 1] = rr.y - sbf[4 * rg + 1];
          accA[4 * rg + 2] = rr.z - sbf[4 * rg + 2];
          accA[4 * rg + 3] = rr.w - sbf[4 * rg + 3];
        }
#pragma unroll
        for (int kt = 0; kt < 16; ++kt) {
          f16x8 uu = *reinterpret_cast<const f16x8*>(ur + kt * 16);
          f16x8 d = uu - vf[kt];
          i32x4 di = __builtin_bit_cast(i32x4, d);
          di &= 0x7fff7fff;
          accA = __builtin_amdgcn_mfma_f32_32x32x16_f16(
              w1f[kt], __builtin_bit_cast(f16x8, di), accA, 0, 0, 0);
        }
        float p = 0.f;
#pragma unroll
        for (int r = 0; r < 16; ++r) {
          float s = accA[r];
          float h = fmaxf(s, 0.01f * s);
          p = fmaf(h, w2f[r], p);
        }
        p += __shfl_xor(p, 32, 64);
        if (l < 32) lds_p[ph][j][ws][l31] = p;
      }
      __syncthreads();
      if (tid < 128) {
        int al = tid >> 5, b = tid & 31;
        float s = b2v;
#pragma unroll
        for (int w = 0; w < 8; ++w) s += lds_p[ph][al][w][b];
        int a = aq * 64 + bt * 4 + al;
        out[(size_t)(n * 256 + a) * 256 + bblk * 32 + b] = 1.f / (1.f + __expf(-s));
      }
    }
  }
}

// ---------------------------------------------------------------------------
// Reduce kernel (MODE 0 only): out = sigmoid(sum_8 pws + b2).
// ---------------------------------------------------------------------------
__global__ __launch_bounds__(256) void reduce_kernel(
    const float* __restrict__ pws, const float* __restrict__ b2,
    float* __restrict__ out) {
  int o = blockIdx.x * 256 + threadIdx.x;     // (n,a,b) flat
  int n = o >> 16, a = (o >> 8) & 255, b = o & 255;
  int bblk = b >> 5, b32 = b & 31, aq = a >> 6, it = a & 63;
  int mbid = (n << 5) | (bblk << 2) | aq;
  const float* p = pws + (((size_t)mbid * 64 + it) * 8) * 32 + b32;
  float s = b2[0];
#pragma unroll
  for (int w = 0; w < 8; ++w) s += p[w * 32];
  out[o] = 1.f / (1.f + __expf(-s));
}

extern "C" void kernel_launch(void* const* d_in, const int* in_sizes, int n_in,
                              void* d_out, int out_size, void* d_ws, size_t ws_size,
                              hipStream_t stream) {
  const float* za = (const float*)d_in[0];
  const float* zb = (const float*)d_in[1];
  const float* w0 = (const float*)d_in[2];
  const float* b0 = (const float*)d_in[3];
  const float* w1 = (const float*)d_in[4];
  const float* b1 = (const float*)d_in[5];
  const float* w2 = (const float*)d_in[6];
  const float* b2 = (const float*)d_in[7];
  float* out = (float*)d_out;

  char* ws = (char*)d_ws;
  _Float16* upack = (_Float16*)ws;                        // 1 MB @ 0
  _Float16* vpack = (_Float16*)(ws + (1u << 20));         // 1 MB @ 1M
  _Float16* vlin  = (_Float16*)(ws + (2u << 20));         // 1 MB @ 2M
  _Float16* w1pk  = (_Float16*)(ws + (3u << 20));         // 128 KB @ 3M
  float*    Ra    = (float*)(ws + (7u << 19));            // 2 MB @ 3.5M
  float*    Sb    = (float*)(ws + (11u << 19));           // 2 MB @ 5.5M
  float*    pws   = (float*)(ws + (15u << 19));           // 16 MB @ 7.5M

  pack_all<<<2304, 256, 0, stream>>>(za, zb, w0, b0, w1, upack, vpack, vlin, w1pk);
  pq_kernel<<<1024, 256, 0, stream>>>(upack, vlin, w1, b1, Ra, Sb);

  const size_t need = (15ull << 19) + 256ull * 64 * 8 * 32 * 4;  // 24.25 MB
  if (ws_size >= need) {
    fused_main<0><<<256, 512, 0, stream>>>(upack, vpack, w1pk, Ra, Sb, w2, b2, pws, out);
    reduce_kernel<<<2048, 256, 0, stream>>>(pws, b2, out);
  } else {
    fused_main<1><<<256, 512, 0, stream>>>(upack, vpack, w1pk, Ra, Sb, w2, b2, nullptr, out);
  }
}